// Round 4
// baseline (419.008 us; speedup 1.0000x reference)
//
#include <hip/hip_runtime.h>
#include <hip/hip_bf16.h>

// SelfAttention fp32 I/O, bf16 MFMA internals.
// R4: attn redesigned around S^T = K Q^T and O^T = V^T P^T with mfma_32x32x16:
// all K/Q/V fragments load b128 straight from global (no LDS staging, NO barriers
// in the k-loop); softmax state is per-lane (q = lane&31); only P bounces through
// a per-wave XOR-swizzled LDS tile (conflict-free). V transposed by a standalone
// batched pass instead of the QKV-epilogue scatter.

typedef unsigned short ushort_t;
typedef __attribute__((ext_vector_type(8))) short short8;
typedef __attribute__((ext_vector_type(4))) float floatx4;
typedef __attribute__((ext_vector_type(16))) float floatx16;

#define NH   16
#define SEQ  2048
#define EMB  1024
#define HDIM 64

#define MFMA32(a, b, c) __builtin_amdgcn_mfma_f32_32x32x16_bf16(a, b, c, 0, 0, 0)

__device__ __forceinline__ ushort_t f2bf(float f) {
    union { float f; unsigned u; } v; v.f = f;
    unsigned r = (v.u + 0x7fffu + ((v.u >> 16) & 1u)) >> 16;  // RNE
    return (ushort_t)r;
}

#if defined(__has_builtin) && __has_builtin(__builtin_amdgcn_global_load_lds)
#define HAS_GLL 1
__device__ __forceinline__ void gload16(const ushort_t* g, ushort_t* l) {
    __builtin_amdgcn_global_load_lds((const __attribute__((address_space(1))) void*)g,
                                     (__attribute__((address_space(3))) void*)l, 16, 0, 0);
}
#else
#define HAS_GLL 0
#endif

// ---------------- fp32 -> bf16 cast (8 elems/thread) ----------------
__global__ __launch_bounds__(256) void cast_k(const float* __restrict__ in,
                                              ushort_t* __restrict__ out) {
    int i = blockIdx.x * 256 + threadIdx.x;
    float4 v0 = ((const float4*)in)[i * 2];
    float4 v1 = ((const float4*)in)[i * 2 + 1];
    short8 t;
    t[0] = (short)f2bf(v0.x); t[1] = (short)f2bf(v0.y);
    t[2] = (short)f2bf(v0.z); t[3] = (short)f2bf(v0.w);
    t[4] = (short)f2bf(v1.x); t[5] = (short)f2bf(v1.y);
    t[6] = (short)f2bf(v1.z); t[7] = (short)f2bf(v1.w);
    ((short8*)out)[i] = t;
}

// ---------------- transpose + fp32->bf16 cast ----------------
__global__ void transpose_cast_k(const float* __restrict__ in, ushort_t* __restrict__ out,
                                 int R, int Cc) {
    __shared__ ushort_t tile[32][33];
    int x  = blockIdx.x * 32 + threadIdx.x;
    int y0 = blockIdx.y * 32;
#pragma unroll
    for (int i = 0; i < 32; i += 8)
        tile[threadIdx.y + i][threadIdx.x] = f2bf(in[(size_t)(y0 + threadIdx.y + i) * Cc + x]);
    __syncthreads();
    int xo = blockIdx.y * 32 + threadIdx.x;
    int yo = blockIdx.x * 32;
#pragma unroll
    for (int i = 0; i < 32; i += 8)
        out[(size_t)(yo + threadIdx.y + i) * R + xo] = tile[threadIdx.x][threadIdx.y + i];
}

// ---------------- batched V transpose: Vb[bh][c][d] -> Vt[bh][d][c] ----------------
__global__ void transpose_v_k(const ushort_t* __restrict__ in, ushort_t* __restrict__ out) {
    __shared__ ushort_t tile[32][33];
    int bh = blockIdx.z;
    int c0 = blockIdx.x * 32, d0 = blockIdx.y * 32;
#pragma unroll
    for (int i = 0; i < 32; i += 8)
        tile[threadIdx.y + i][threadIdx.x] =
            in[((size_t)bh * SEQ + c0 + threadIdx.y + i) * HDIM + d0 + threadIdx.x];
    __syncthreads();
#pragma unroll
    for (int i = 0; i < 32; i += 8)
        out[((size_t)bh * HDIM + d0 + threadIdx.y + i) * SEQ + c0 + threadIdx.x] =
            tile[threadIdx.x][threadIdx.y + i];
}

// ---------------- GEMM: C[m][n] = sum_k A[m][k] * Bt[n][k] (both bf16) ----------------
// 128x128 tile, 256 thr, BK=64, global_load_lds + XOR-swizzled LDS (round-3 verified).
// EPI=0: fp32 store. EPI=1: uniform bf16 QKV scatter: O[which][(bh*SEQ+c)*64+d].
template<int EPI>
__global__ __launch_bounds__(256) void gemm_bt(const ushort_t* __restrict__ A,
                                               const ushort_t* __restrict__ Bt,
                                               void* __restrict__ O0v,
                                               ushort_t* __restrict__ O1,
                                               ushort_t* __restrict__ O2,
                                               int M, int N, int K) {
    __shared__ __align__(16) ushort_t As[128 * 64];
    __shared__ __align__(16) ushort_t Bs[128 * 64];
    const int tid  = threadIdx.x;
    const int wv   = tid >> 6, lane = tid & 63, quad = lane >> 4, l15 = lane & 15;
    const int wm   = wv >> 1, wn = wv & 1;
    const int bm   = blockIdx.x, bn = blockIdx.y;
    const int lrow = lane >> 3;
    const int kg   = (lane & 7) ^ (lrow & 7);
    const int sw   = l15 & 7;

    floatx4 acc[4][4];
#pragma unroll
    for (int i = 0; i < 4; i++)
#pragma unroll
        for (int j = 0; j < 4; j++) acc[i][j] = (floatx4){0.f, 0.f, 0.f, 0.f};

    for (int kt = 0; kt < K; kt += 64) {
#pragma unroll
        for (int it = 0; it < 4; it++) {
            int r0 = it * 32 + wv * 8;
            const ushort_t* ga = &A [(size_t)(bm * 128 + r0 + lrow) * K + kt + kg * 8];
            const ushort_t* gb = &Bt[(size_t)(bn * 128 + r0 + lrow) * K + kt + kg * 8];
#if HAS_GLL
            gload16(ga, &As[r0 * 64]);
            gload16(gb, &Bs[r0 * 64]);
#else
            *(uint4*)&As[(r0 + lrow) * 64 + (lane & 7) * 8] = *(const uint4*)ga;
            *(uint4*)&Bs[(r0 + lrow) * 64 + (lane & 7) * 8] = *(const uint4*)gb;
#endif
        }
        __syncthreads();
#pragma unroll
        for (int ks = 0; ks < 2; ks++) {
            short8 af[4], bf[4];
#pragma unroll
            for (int i = 0; i < 4; i++)
                af[i] = *(const short8*)&As[(wm * 64 + i * 16 + l15) * 64 + (((ks * 4 + quad) ^ sw) * 8)];
#pragma unroll
            for (int j = 0; j < 4; j++)
                bf[j] = *(const short8*)&Bs[(wn * 64 + j * 16 + l15) * 64 + (((ks * 4 + quad) ^ sw) * 8)];
#pragma unroll
            for (int i = 0; i < 4; i++)
#pragma unroll
                for (int j = 0; j < 4; j++)
                    acc[i][j] = __builtin_amdgcn_mfma_f32_16x16x32_bf16(af[i], bf[j], acc[i][j], 0, 0, 0);
        }
        __syncthreads();
    }

#pragma unroll
    for (int i = 0; i < 4; i++)
#pragma unroll
        for (int j = 0; j < 4; j++)
#pragma unroll
            for (int r = 0; r < 4; r++) {
                int row = bm * 128 + wm * 64 + i * 16 + quad * 4 + r;   // C/D: row=quad*4+reg
                int col = bn * 128 + wn * 64 + j * 16 + l15;
                if (EPI == 0) {
                    ((float*)O0v)[(size_t)row * N + col] = acc[i][j][r];
                } else {
                    ushort_t v = f2bf(acc[i][j][r]);
                    int b = row >> 11, c = row & 2047;
                    int which = col >> 10, nn = col & 1023;
                    int hh = nn >> 6, d = nn & 63;
                    ushort_t* dst = (which == 0) ? (ushort_t*)O0v : (which == 1) ? O1 : O2;
                    dst[((size_t)(b * NH + hh) * SEQ + c) * HDIM + d] = v;
                }
            }
}

// ---------------- flash attention v2: S^T / O^T, 32x32x16, barrier-free ----------------
// grid (16 qb, 64 bh); 4 waves; wave w owns q rows [qb*128 + 32w, +32).
// S^T = K Q^T: C col = q = lane&31 -> per-lane softmax state.
// O^T = V^T P^T: C col = q as well -> per-lane rescale, no shuffles.
__global__ __launch_bounds__(256) void attn2_k(const ushort_t* __restrict__ Qg,
                                               const ushort_t* __restrict__ Kg,
                                               const ushort_t* __restrict__ Vtg,
                                               ushort_t* __restrict__ Y) {
    __shared__ __align__(16) ushort_t Ps[4][32 * 64];   // per-wave P / epilogue bounce
    const int tid  = threadIdx.x;
    const int wv   = tid >> 6, lane = tid & 63;
    const int l31  = lane & 31, hf = lane >> 5;         // half-wave
    const int qb   = blockIdx.x, bh = blockIdx.y;
    const int qrow0 = qb * 128 + wv * 32;
    const int q_abs = qrow0 + l31;
    const int qs7   = l31 & 7;                          // P swizzle key
    ushort_t* Pw = Ps[wv];

    // Q B-frags (n=q=l31, k = ks*16 + hf*8 + j), loaded once
    short8 qf[4];
    {
        const ushort_t* qb_ = Qg + ((size_t)bh * SEQ + q_abs) * HDIM + hf * 8;
#pragma unroll
        for (int ks = 0; ks < 4; ks++) qf[ks] = *(const short8*)(qb_ + ks * 16);
    }

    floatx16 o0 = {0.f}, o1 = {0.f};                    // O^T d-tiles (d 0..31 / 32..63)
#pragma unroll
    for (int r = 0; r < 16; r++) { o0[r] = 0.f; o1[r] = 0.f; }
    float m_i = -1e30f, l_i = 0.f;
    const float c2 = 0.18033688011112042f;              // 0.125 * log2(e)

    const int jmax = (qrow0 + 31) >> 6;
    for (int j = 0; j <= jmax; j++) {
        // ---- S^T = K Q^T (A = K rows = keys, direct b128 from global) ----
        const ushort_t* kb_ = Kg + ((size_t)bh * SEQ + j * 64 + l31) * HDIM + hf * 8;
        floatx16 s0 = {0.f}, s1 = {0.f};
#pragma unroll
        for (int r = 0; r < 16; r++) { s0[r] = 0.f; s1[r] = 0.f; }
#pragma unroll
        for (int ks = 0; ks < 4; ks++) {
            short8 k0 = *(const short8*)(kb_ + ks * 16);
            short8 k1 = *(const short8*)(kb_ + 32 * HDIM + ks * 16);
            s0 = MFMA32(k0, qf[ks], s0);
            s1 = MFMA32(k1, qf[ks], s1);
        }

        // ---- V^T A-frags issued early (latency hidden under softmax VALU) ----
        const ushort_t* vb_ = Vtg + ((size_t)bh * HDIM + l31) * SEQ + j * 64 + hf * 8;
        short8 vf0[4], vf1[4];
#pragma unroll
        for (int ks = 0; ks < 4; ks++) {
            vf0[ks] = *(const short8*)(vb_ + ks * 16);
            vf1[ks] = *(const short8*)(vb_ + 32 * SEQ + ks * 16);
        }

        // ---- scale (+ causal mask on the last tile); log2-domain ----
        if (j == jmax) {
            const int kb0 = j * 64 + 4 * hf;
#pragma unroll
            for (int r = 0; r < 16; r++) {
                int key = kb0 + (r & 3) + 8 * (r >> 2);
                s0[r] = (key > q_abs) ? -1e30f : s0[r] * c2;
                s1[r] = (key + 32 > q_abs) ? -1e30f : s1[r] * c2;
            }
        } else {
#pragma unroll
            for (int r = 0; r < 16; r++) { s0[r] *= c2; s1[r] *= c2; }
        }

        // ---- per-lane softmax over 32 scores + partner half-wave ----
        float mx = -1e30f;
#pragma unroll
        for (int r = 0; r < 16; r++) mx = fmaxf(mx, fmaxf(s0[r], s1[r]));
        mx = fmaxf(mx, __shfl_xor(mx, 32));
        float m_new = fmaxf(m_i, mx);
        float alpha = __builtin_amdgcn_exp2f(m_i - m_new);
        m_i = m_new;

        float rs = 0.f;
#pragma unroll
        for (int r = 0; r < 16; r++) {
            s0[r] = __builtin_amdgcn_exp2f(s0[r] - m_new);
            s1[r] = __builtin_amdgcn_exp2f(s1[r] - m_new);
            rs += s0[r] + s1[r];
        }
        rs += __shfl_xor(rs, 32);
        l_i = l_i * alpha + rs;

        // ---- P -> LDS (C-layout reg quads = 4 consecutive keys; XOR-swizzled) ----
#pragma unroll
        for (int g = 0; g < 4; g++) {
            uint2 w0, w1;
            w0.x = (unsigned)f2bf(s0[g * 4])     | ((unsigned)f2bf(s0[g * 4 + 1]) << 16);
            w0.y = (unsigned)f2bf(s0[g * 4 + 2]) | ((unsigned)f2bf(s0[g * 4 + 3]) << 16);
            w1.x = (unsigned)f2bf(s1[g * 4])     | ((unsigned)f2bf(s1[g * 4 + 1]) << 16);
            w1.y = (unsigned)f2bf(s1[g * 4 + 2]) | ((unsigned)f2bf(s1[g * 4 + 3]) << 16);
            *(uint2*)&Pw[l31 * 64 + ((g     ^ qs7) * 8) + 4 * hf] = w0;   // keys 8g+4hf+{0..3}
            *(uint2*)&Pw[l31 * 64 + (((4+g) ^ qs7) * 8) + 4 * hf] = w1;   // +32
        }

        // ---- rescale O^T by own alpha (no shuffles) ----
#pragma unroll
        for (int r = 0; r < 16; r++) { o0[r] *= alpha; o1[r] *= alpha; }

        // ---- O^T += V^T P^T ----
#pragma unroll
        for (int ks = 0; ks < 4; ks++) {
            short8 pf = *(const short8*)&Pw[l31 * 64 + (((ks * 2 + hf) ^ qs7) * 8)];
            o0 = MFMA32(vf0[ks], pf, o0);
            o1 = MFMA32(vf1[ks], pf, o1);
        }
    }

    // ---- epilogue: divide by l, transpose via per-wave LDS, coalesced store ----
    float inv = 1.0f / l_i;
#pragma unroll
    for (int g = 0; g < 4; g++) {
        uint2 w0, w1;
        w0.x = (unsigned)f2bf(o0[g * 4] * inv)     | ((unsigned)f2bf(o0[g * 4 + 1] * inv) << 16);
        w0.y = (unsigned)f2bf(o0[g * 4 + 2] * inv) | ((unsigned)f2bf(o0[g * 4 + 3] * inv) << 16);
        w1.x = (unsigned)f2bf(o1[g * 4] * inv)     | ((unsigned)f2bf(o1[g * 4 + 1] * inv) << 16);
        w1.y = (unsigned)f2bf(o1[g * 4 + 2] * inv) | ((unsigned)f2bf(o1[g * 4 + 3] * inv) << 16);
        *(uint2*)&Pw[l31 * 64 + ((g     ^ qs7) * 8) + 4 * hf] = w0;   // d 8g+4hf+{0..3}
        *(uint2*)&Pw[l31 * 64 + (((4+g) ^ qs7) * 8) + 4 * hf] = w1;   // d+32
    }
    const int b = bh >> 4, hh = bh & 15;
    const int dg = lane & 7;
#pragma unroll
    for (int sb = 0; sb < 4; sb++) {
        int ql = sb * 8 + (lane >> 3);
        uint4 v = *(const uint4*)&Pw[ql * 64 + ((dg ^ (ql & 7)) * 8)];
        *(uint4*)&Y[((size_t)(b * SEQ + qrow0 + ql)) * EMB + hh * HDIM + dg * 8] = v;
    }
}

// ---------------- launch ----------------
extern "C" void kernel_launch(void* const* d_in, const int* in_sizes, int n_in,
                              void* d_out, int out_size, void* d_ws, size_t ws_size,
                              hipStream_t stream) {
    const float* x      = (const float*)d_in[0];   // [8192][1024] fp32
    const float* W_attn = (const float*)d_in[1];   // [1024][3072] fp32
    const float* W_proj = (const float*)d_in[2];   // [1024][1024] fp32

    char* ws = (char*)d_ws;
    ushort_t* Wt_attn = (ushort_t*)(ws);                 // [3072][1024] bf16  6.3 MB
    ushort_t* Wt_proj = (ushort_t*)(ws + 6291456);       // [1024][1024] bf16  2.1 MB
    ushort_t* Xb      = (ushort_t*)(ws + 8388608);       // [8192][1024] bf16 16.8 MB
    ushort_t* Vt      = Xb;                              // alias: Xb dead after QKV gemm
    ushort_t* Qb      = (ushort_t*)(ws + 25165824);      // [64][2048][64]
    ushort_t* Kb      = (ushort_t*)(ws + 41943040);      // [64][2048][64]
    ushort_t* Vb      = (ushort_t*)(ws + 58720256);      // [64][2048][64]
    ushort_t* Yb      = Vb;                              // alias: Vb dead after transpose_v
    // total ws use: 75,497,472 B

    cast_k<<<4096, 256, 0, stream>>>(x, Xb);
    transpose_cast_k<<<dim3(3072 / 32, 1024 / 32), dim3(32, 8), 0, stream>>>(W_attn, Wt_attn, 1024, 3072);
    transpose_cast_k<<<dim3(1024 / 32, 1024 / 32), dim3(32, 8), 0, stream>>>(W_proj, Wt_proj, 1024, 1024);
    gemm_bt<1><<<dim3(8192 / 128, 3072 / 128), 256, 0, stream>>>(Xb, Wt_attn, Qb, Kb, Vb, 8192, 3072, 1024);
    transpose_v_k<<<dim3(SEQ / 32, HDIM / 32, 64), dim3(32, 8), 0, stream>>>(Vb, Vt);
    attn2_k<<<dim3(16, 64), 256, 0, stream>>>(Qb, Kb, Vt, Yb);
    gemm_bt<0><<<dim3(8192 / 128, 1024 / 128), 256, 0, stream>>>(Yb, Wt_proj, d_out,
                                                                 nullptr, nullptr, 8192, 1024, 1024);
}

// Round 5
// 267.747 us; speedup vs baseline: 1.5649x; 1.5649x over previous
//
#include <hip/hip_runtime.h>
#include <hip/hip_bf16.h>

// SelfAttention fp32 I/O, bf16 MFMA internals.
// R5: attn keeps the verified 32x32 S^T/O^T per-lane-softmax engine from R4 but
// restores block-level LDS staging of K/V (global_load_lds + XOR swizzle, shared
// by 4 waves) and balances load by pairing q-supertiles {z, 15-z} inside each
// block (grid 8x64, every block = exactly 36 j-tiles).

typedef unsigned short ushort_t;
typedef __attribute__((ext_vector_type(8))) short short8;
typedef __attribute__((ext_vector_type(4))) float floatx4;
typedef __attribute__((ext_vector_type(16))) float floatx16;

#define NH   16
#define SEQ  2048
#define EMB  1024
#define HDIM 64

#define MFMA32(a, b, c) __builtin_amdgcn_mfma_f32_32x32x16_bf16(a, b, c, 0, 0, 0)

__device__ __forceinline__ ushort_t f2bf(float f) {
    union { float f; unsigned u; } v; v.f = f;
    unsigned r = (v.u + 0x7fffu + ((v.u >> 16) & 1u)) >> 16;  // RNE
    return (ushort_t)r;
}

#if defined(__has_builtin) && __has_builtin(__builtin_amdgcn_global_load_lds)
#define HAS_GLL 1
__device__ __forceinline__ void gload16(const ushort_t* g, ushort_t* l) {
    __builtin_amdgcn_global_load_lds((const __attribute__((address_space(1))) void*)g,
                                     (__attribute__((address_space(3))) void*)l, 16, 0, 0);
}
#else
#define HAS_GLL 0
#endif

// ---------------- fp32 -> bf16 cast (8 elems/thread) ----------------
__global__ __launch_bounds__(256) void cast_k(const float* __restrict__ in,
                                              ushort_t* __restrict__ out) {
    int i = blockIdx.x * 256 + threadIdx.x;
    float4 v0 = ((const float4*)in)[i * 2];
    float4 v1 = ((const float4*)in)[i * 2 + 1];
    short8 t;
    t[0] = (short)f2bf(v0.x); t[1] = (short)f2bf(v0.y);
    t[2] = (short)f2bf(v0.z); t[3] = (short)f2bf(v0.w);
    t[4] = (short)f2bf(v1.x); t[5] = (short)f2bf(v1.y);
    t[6] = (short)f2bf(v1.z); t[7] = (short)f2bf(v1.w);
    ((short8*)out)[i] = t;
}

// ---------------- transpose + fp32->bf16 cast ----------------
__global__ void transpose_cast_k(const float* __restrict__ in, ushort_t* __restrict__ out,
                                 int R, int Cc) {
    __shared__ ushort_t tile[32][33];
    int x  = blockIdx.x * 32 + threadIdx.x;
    int y0 = blockIdx.y * 32;
#pragma unroll
    for (int i = 0; i < 32; i += 8)
        tile[threadIdx.y + i][threadIdx.x] = f2bf(in[(size_t)(y0 + threadIdx.y + i) * Cc + x]);
    __syncthreads();
    int xo = blockIdx.y * 32 + threadIdx.x;
    int yo = blockIdx.x * 32;
#pragma unroll
    for (int i = 0; i < 32; i += 8)
        out[(size_t)(yo + threadIdx.y + i) * R + xo] = tile[threadIdx.x][threadIdx.y + i];
}

// ---------------- batched V transpose: Vb[bh][c][d] -> Vt[bh][d][c] ----------------
__global__ void transpose_v_k(const ushort_t* __restrict__ in, ushort_t* __restrict__ out) {
    __shared__ ushort_t tile[32][33];
    int bh = blockIdx.z;
    int c0 = blockIdx.x * 32, d0 = blockIdx.y * 32;
#pragma unroll
    for (int i = 0; i < 32; i += 8)
        tile[threadIdx.y + i][threadIdx.x] =
            in[((size_t)bh * SEQ + c0 + threadIdx.y + i) * HDIM + d0 + threadIdx.x];
    __syncthreads();
#pragma unroll
    for (int i = 0; i < 32; i += 8)
        out[((size_t)bh * HDIM + d0 + threadIdx.y + i) * SEQ + c0 + threadIdx.x] =
            tile[threadIdx.x][threadIdx.y + i];
}

// ---------------- GEMM: C[m][n] = sum_k A[m][k] * Bt[n][k] (both bf16) ----------------
template<int EPI>
__global__ __launch_bounds__(256) void gemm_bt(const ushort_t* __restrict__ A,
                                               const ushort_t* __restrict__ Bt,
                                               void* __restrict__ O0v,
                                               ushort_t* __restrict__ O1,
                                               ushort_t* __restrict__ O2,
                                               int M, int N, int K) {
    __shared__ __align__(16) ushort_t As[128 * 64];
    __shared__ __align__(16) ushort_t Bs[128 * 64];
    const int tid  = threadIdx.x;
    const int wv   = tid >> 6, lane = tid & 63, quad = lane >> 4, l15 = lane & 15;
    const int wm   = wv >> 1, wn = wv & 1;
    const int bm   = blockIdx.x, bn = blockIdx.y;
    const int lrow = lane >> 3;
    const int kg   = (lane & 7) ^ (lrow & 7);
    const int sw   = l15 & 7;

    floatx4 acc[4][4];
#pragma unroll
    for (int i = 0; i < 4; i++)
#pragma unroll
        for (int j = 0; j < 4; j++) acc[i][j] = (floatx4){0.f, 0.f, 0.f, 0.f};

    for (int kt = 0; kt < K; kt += 64) {
#pragma unroll
        for (int it = 0; it < 4; it++) {
            int r0 = it * 32 + wv * 8;
            const ushort_t* ga = &A [(size_t)(bm * 128 + r0 + lrow) * K + kt + kg * 8];
            const ushort_t* gb = &Bt[(size_t)(bn * 128 + r0 + lrow) * K + kt + kg * 8];
#if HAS_GLL
            gload16(ga, &As[r0 * 64]);
            gload16(gb, &Bs[r0 * 64]);
#else
            *(uint4*)&As[(r0 + lrow) * 64 + (lane & 7) * 8] = *(const uint4*)ga;
            *(uint4*)&Bs[(r0 + lrow) * 64 + (lane & 7) * 8] = *(const uint4*)gb;
#endif
        }
        __syncthreads();
#pragma unroll
        for (int ks = 0; ks < 2; ks++) {
            short8 af[4], bf[4];
#pragma unroll
            for (int i = 0; i < 4; i++)
                af[i] = *(const short8*)&As[(wm * 64 + i * 16 + l15) * 64 + (((ks * 4 + quad) ^ sw) * 8)];
#pragma unroll
            for (int j = 0; j < 4; j++)
                bf[j] = *(const short8*)&Bs[(wn * 64 + j * 16 + l15) * 64 + (((ks * 4 + quad) ^ sw) * 8)];
#pragma unroll
            for (int i = 0; i < 4; i++)
#pragma unroll
                for (int j = 0; j < 4; j++)
                    acc[i][j] = __builtin_amdgcn_mfma_f32_16x16x32_bf16(af[i], bf[j], acc[i][j], 0, 0, 0);
        }
        __syncthreads();
    }

#pragma unroll
    for (int i = 0; i < 4; i++)
#pragma unroll
        for (int j = 0; j < 4; j++)
#pragma unroll
            for (int r = 0; r < 4; r++) {
                int row = bm * 128 + wm * 64 + i * 16 + quad * 4 + r;   // C/D: row=quad*4+reg
                int col = bn * 128 + wn * 64 + j * 16 + l15;
                if (EPI == 0) {
                    ((float*)O0v)[(size_t)row * N + col] = acc[i][j][r];
                } else {
                    ushort_t v = f2bf(acc[i][j][r]);
                    int b = row >> 11, c = row & 2047;
                    int which = col >> 10, nn = col & 1023;
                    int hh = nn >> 6, d = nn & 63;
                    ushort_t* dst = (which == 0) ? (ushort_t*)O0v : (which == 1) ? O1 : O2;
                    dst[((size_t)(b * NH + hh) * SEQ + c) * HDIM + d] = v;
                }
            }
}

// ---------------- flash attention v3: S^T/O^T 32x32, LDS-staged K/V, paired qb ----------
// grid (8 z, 64 bh); 256 thr = 4 waves. Block processes qb = z then qb = 15-z
// (exactly 36 j-tiles per block -> perfect balance). Per j-tile, K[64][64] and
// V^T[64][64] are staged once to LDS (global_load_lds, XOR-swizzled chunks) and
// shared by all 4 waves. Softmax state per lane (q = lane&31). P bounces through
// a per-wave swizzled LDS tile.
__global__ __launch_bounds__(256) void attn3_k(const ushort_t* __restrict__ Qg,
                                               const ushort_t* __restrict__ Kg,
                                               const ushort_t* __restrict__ Vtg,
                                               ushort_t* __restrict__ Y) {
    __shared__ __align__(16) ushort_t Ks[64 * 64];      // [key][d], chunk-swizzled
    __shared__ __align__(16) ushort_t Vs[64 * 64];      // [d][key], chunk-swizzled
    __shared__ __align__(16) ushort_t Ps[4][32 * 64];   // per-wave P / epilogue bounce
    const int tid  = threadIdx.x;
    const int wv   = tid >> 6, lane = tid & 63;
    const int l31  = lane & 31, hf = lane >> 5;
    const int z    = blockIdx.x, bh = blockIdx.y;
    const int qs7  = l31 & 7;
    const int lrow = lane >> 3;                 // staging row-in-chunk
    const int kgs  = (lane & 7) ^ (lrow & 7);   // staging global chunk (XOR swizzle)
    ushort_t* Pw = Ps[wv];
    const int b = bh >> 4, hh = bh & 15;
    const float c2 = 0.18033688011112042f;      // 0.125 * log2(e)

    for (int pp = 0; pp < 2; pp++) {
        const int qb = pp ? (15 - z) : z;
        const int qrow0 = qb * 128 + wv * 32;
        const int q_abs = qrow0 + l31;
        const int jmax_w = 2 * qb + (wv >> 1);  // waves 2,3 reach one tile further
        const int jmax_b = 2 * qb + 1;

        // Q B-frags (n=q=l31, k = ks*16 + hf*8 + j), once per qb
        short8 qf[4];
        {
            const ushort_t* qp = Qg + ((size_t)bh * SEQ + q_abs) * HDIM + hf * 8;
#pragma unroll
            for (int ks = 0; ks < 4; ks++) qf[ks] = *(const short8*)(qp + ks * 16);
        }

        floatx16 o0, o1;
#pragma unroll
        for (int r = 0; r < 16; r++) { o0[r] = 0.f; o1[r] = 0.f; }
        float m_i = -1e30f, l_i = 0.f;

        for (int j = 0; j <= jmax_b; j++) {
            // ---- stage K tile + V^T tile (16 KB) cooperatively ----
#pragma unroll
            for (int it = 0; it < 2; it++) {
                int r0 = it * 32 + wv * 8;
                const ushort_t* gk = &Kg [((size_t)bh * SEQ  + j * 64 + r0 + lrow) * HDIM + kgs * 8];
                const ushort_t* gv = &Vtg[((size_t)bh * HDIM + r0 + lrow) * SEQ + j * 64 + kgs * 8];
#if HAS_GLL
                gload16(gk, &Ks[r0 * 64]);
                gload16(gv, &Vs[r0 * 64]);
#else
                *(uint4*)&Ks[(r0 + lrow) * 64 + (lane & 7) * 8] = *(const uint4*)gk;
                *(uint4*)&Vs[(r0 + lrow) * 64 + (lane & 7) * 8] = *(const uint4*)gv;
#endif
            }
            __syncthreads();

            if (j <= jmax_w) {
                // ---- S^T = K Q^T (A-frags from swizzled LDS) ----
                floatx16 s0, s1;
#pragma unroll
                for (int r = 0; r < 16; r++) { s0[r] = 0.f; s1[r] = 0.f; }
#pragma unroll
                for (int ks = 0; ks < 4; ks++) {
                    int slot = ((hf + 2 * ks) ^ qs7) * 8;
                    short8 k0 = *(const short8*)&Ks[l31 * 64 + slot];
                    short8 k1 = *(const short8*)&Ks[(32 + l31) * 64 + slot];
                    s0 = MFMA32(k0, qf[ks], s0);
                    s1 = MFMA32(k1, qf[ks], s1);
                }

                // ---- scale (+ causal mask on own boundary tile) ----
                if (j == jmax_w) {
                    const int kb0 = j * 64 + 4 * hf;
#pragma unroll
                    for (int r = 0; r < 16; r++) {
                        int key = kb0 + (r & 3) + 8 * (r >> 2);
                        s0[r] = (key > q_abs) ? -1e30f : s0[r] * c2;
                        s1[r] = (key + 32 > q_abs) ? -1e30f : s1[r] * c2;
                    }
                } else {
#pragma unroll
                    for (int r = 0; r < 16; r++) { s0[r] *= c2; s1[r] *= c2; }
                }

                // ---- per-lane softmax (32 scores) + partner half-wave ----
                float mx = -1e30f;
#pragma unroll
                for (int r = 0; r < 16; r++) mx = fmaxf(mx, fmaxf(s0[r], s1[r]));
                mx = fmaxf(mx, __shfl_xor(mx, 32));
                float m_new = fmaxf(m_i, mx);
                float alpha = __builtin_amdgcn_exp2f(m_i - m_new);
                m_i = m_new;

                float rs = 0.f;
#pragma unroll
                for (int r = 0; r < 16; r++) {
                    s0[r] = __builtin_amdgcn_exp2f(s0[r] - m_new);
                    s1[r] = __builtin_amdgcn_exp2f(s1[r] - m_new);
                    rs += s0[r] + s1[r];
                }
                rs += __shfl_xor(rs, 32);
                l_i = l_i * alpha + rs;

                // ---- P -> per-wave LDS (C-layout quads = 4 consecutive keys) ----
#pragma unroll
                for (int g = 0; g < 4; g++) {
                    uint2 w0, w1;
                    w0.x = (unsigned)f2bf(s0[g * 4])     | ((unsigned)f2bf(s0[g * 4 + 1]) << 16);
                    w0.y = (unsigned)f2bf(s0[g * 4 + 2]) | ((unsigned)f2bf(s0[g * 4 + 3]) << 16);
                    w1.x = (unsigned)f2bf(s1[g * 4])     | ((unsigned)f2bf(s1[g * 4 + 1]) << 16);
                    w1.y = (unsigned)f2bf(s1[g * 4 + 2]) | ((unsigned)f2bf(s1[g * 4 + 3]) << 16);
                    *(uint2*)&Pw[l31 * 64 + ((g     ^ qs7) * 8) + 4 * hf] = w0;
                    *(uint2*)&Pw[l31 * 64 + (((4+g) ^ qs7) * 8) + 4 * hf] = w1;
                }

                // ---- rescale O^T (per-lane alpha, no shuffles) ----
#pragma unroll
                for (int r = 0; r < 16; r++) { o0[r] *= alpha; o1[r] *= alpha; }

                // ---- O^T += V^T P^T ----
#pragma unroll
                for (int ks = 0; ks < 4; ks++) {
                    int slot = ((hf + 2 * ks) ^ qs7) * 8;
                    short8 v0 = *(const short8*)&Vs[l31 * 64 + slot];
                    short8 v1 = *(const short8*)&Vs[(32 + l31) * 64 + slot];
                    short8 pf = *(const short8*)&Pw[l31 * 64 + (((ks * 2 + hf) ^ qs7) * 8)];
                    o0 = MFMA32(v0, pf, o0);
                    o1 = MFMA32(v1, pf, o1);
                }
            }
            __syncthreads();
        }

        // ---- epilogue: /l, transpose via per-wave LDS, coalesced store ----
        float inv = 1.0f / l_i;
#pragma unroll
        for (int g = 0; g < 4; g++) {
            uint2 w0, w1;
            w0.x = (unsigned)f2bf(o0[g * 4] * inv)     | ((unsigned)f2bf(o0[g * 4 + 1] * inv) << 16);
            w0.y = (unsigned)f2bf(o0[g * 4 + 2] * inv) | ((unsigned)f2bf(o0[g * 4 + 3] * inv) << 16);
            w1.x = (unsigned)f2bf(o1[g * 4] * inv)     | ((unsigned)f2bf(o1[g * 4 + 1] * inv) << 16);
            w1.y = (unsigned)f2bf(o1[g * 4 + 2] * inv) | ((unsigned)f2bf(o1[g * 4 + 3] * inv) << 16);
            *(uint2*)&Pw[l31 * 64 + ((g     ^ qs7) * 8) + 4 * hf] = w0;   // d 8g+4hf+{0..3}
            *(uint2*)&Pw[l31 * 64 + (((4+g) ^ qs7) * 8) + 4 * hf] = w1;   // d+32
        }
        const int dg = lane & 7;
#pragma unroll
        for (int sb = 0; sb < 4; sb++) {
            int ql = sb * 8 + (lane >> 3);
            uint4 v = *(const uint4*)&Pw[ql * 64 + ((dg ^ (ql & 7)) * 8)];
            *(uint4*)&Y[((size_t)(b * SEQ + qrow0 + ql)) * EMB + hh * HDIM + dg * 8] = v;
        }
    }
}

// ---------------- launch ----------------
extern "C" void kernel_launch(void* const* d_in, const int* in_sizes, int n_in,
                              void* d_out, int out_size, void* d_ws, size_t ws_size,
                              hipStream_t stream) {
    const float* x      = (const float*)d_in[0];   // [8192][1024] fp32
    const float* W_attn = (const float*)d_in[1];   // [1024][3072] fp32
    const float* W_proj = (const float*)d_in[2];   // [1024][1024] fp32

    char* ws = (char*)d_ws;
    ushort_t* Wt_attn = (ushort_t*)(ws);                 // [3072][1024] bf16  6.3 MB
    ushort_t* Wt_proj = (ushort_t*)(ws + 6291456);       // [1024][1024] bf16  2.1 MB
    ushort_t* Xb      = (ushort_t*)(ws + 8388608);       // [8192][1024] bf16 16.8 MB
    ushort_t* Vt      = Xb;                              // alias: Xb dead after QKV gemm
    ushort_t* Qb      = (ushort_t*)(ws + 25165824);      // [64][2048][64]
    ushort_t* Kb      = (ushort_t*)(ws + 41943040);      // [64][2048][64]
    ushort_t* Vb      = (ushort_t*)(ws + 58720256);      // [64][2048][64]
    ushort_t* Yb      = Vb;                              // alias: Vb dead after transpose_v
    // total ws use: 75,497,472 B

    cast_k<<<4096, 256, 0, stream>>>(x, Xb);
    transpose_cast_k<<<dim3(3072 / 32, 1024 / 32), dim3(32, 8), 0, stream>>>(W_attn, Wt_attn, 1024, 3072);
    transpose_cast_k<<<dim3(1024 / 32, 1024 / 32), dim3(32, 8), 0, stream>>>(W_proj, Wt_proj, 1024, 1024);
    gemm_bt<1><<<dim3(8192 / 128, 3072 / 128), 256, 0, stream>>>(Xb, Wt_attn, Qb, Kb, Vb, 8192, 3072, 1024);
    transpose_v_k<<<dim3(SEQ / 32, HDIM / 32, 64), dim3(32, 8), 0, stream>>>(Vb, Vt);
    attn3_k<<<dim3(8, 64), 256, 0, stream>>>(Qb, Kb, Vt, Yb);
    gemm_bt<0><<<dim3(8192 / 128, 1024 / 128), 256, 0, stream>>>(Yb, Wt_proj, d_out,
                                                                 nullptr, nullptr, 8192, 1024, 1024);
}